// Round 1
// baseline (2886.580 us; speedup 1.0000x reference)
//
#include <hip/hip_runtime.h>

#define T_ 1024
#define B_ 128
#define H_ 128
#define L_ 20
#define G4H_ 512
#define TS 32
#define NCT (T_ / TS)          // 32 time chunks
#define NCH 8                  // batch chunks of 16 rows
#define NSLOT (L_ + NCT - 1)   // 51 wavefront slots

typedef _Float16 f16x8 __attribute__((ext_vector_type(8)));
typedef _Float16 f16x4 __attribute__((ext_vector_type(4)));
typedef float f32x4 __attribute__((ext_vector_type(4)));

__device__ __forceinline__ float fast_sig(float x) {
  float e = __builtin_amdgcn_exp2f(-1.44269504f * x);
  return __builtin_amdgcn_rcpf(1.0f + e);
}
__device__ __forceinline__ float fast_tanh(float x) {
  float e = __builtin_amdgcn_exp2f(2.88539008f * x);  // e^{2x}
  return 1.0f - 2.0f * __builtin_amdgcn_rcpf(e + 1.0f);
}

// fp32 -> fp16 weight copies in workspace (re-done every launch; deterministic)
__global__ void wconv_kernel(const float* __restrict__ Wih, const float* __restrict__ Whh,
                             _Float16* __restrict__ Wif, _Float16* __restrict__ Whf) {
  int i = blockIdx.x * 256 + threadIdx.x;
  if (i < L_ * G4H_ * H_) {
    Wif[i] = (_Float16)Wih[i];
    Whf[i] = (_Float16)Whh[i];
  }
}

// embedding gather: fp32 copy to d_out (output 1) + fp16 copy as layer-0 input
__global__ void emb_kernel(const int* __restrict__ xids, const float* __restrict__ emb,
                           float* __restrict__ out_emb, _Float16* __restrict__ X0) {
  int row = blockIdx.x;       // t*B + b
  int d = threadIdx.x;        // 0..127
  int tok = xids[row];
  float v = emb[(size_t)tok * H_ + d];
  out_emb[(size_t)row * H_ + d] = v;
  X0[(size_t)row * H_ + d] = (_Float16)v;
}

// One wavefront slot: all active (layer l, time-chunk ct = slot - l) tasks.
// Block = 512 threads = 8 waves; block owns (task, 16-row batch chunk).
// Wave w owns hidden slice [16w, 16w+16): 4 gate j-tiles, weights in registers.
__launch_bounds__(512)
__global__ void lstm_slot_kernel(const _Float16* __restrict__ Wif,
                                 const _Float16* __restrict__ Whf,
                                 const float* __restrict__ bih,
                                 const float* __restrict__ bhh,
                                 const _Float16* __restrict__ X0,
                                 _Float16* __restrict__ XR,
                                 float* __restrict__ CS,
                                 float* __restrict__ out_h,
                                 int slot, int l0) {
  const int task = blockIdx.x >> 3;
  const int chunk = blockIdx.x & 7;
  const int l = l0 + task;
  const int ct = slot - l;
  const int lane = threadIdx.x & 63;
  const int wave = threadIdx.x >> 6;
  const int lr = lane & 15;    // A-frag row / B-frag col / D col
  const int lhi = lane >> 4;   // k-group; D row group
  const int k0 = lhi * 8;
  const int ub = wave * 16;    // hidden slice base

  // ---- weight fragments: wi/wh[G][kt], lane holds W[j = G*128+ub+lr][kt*32+k0 .. +8] ----
  f16x8 wi[4][4], wh[4][4];
  float bias[4];
  {
    const _Float16* wip = Wif + (size_t)l * G4H_ * H_;
    const _Float16* whp = Whf + (size_t)l * G4H_ * H_;
#pragma unroll
    for (int G = 0; G < 4; ++G) {
      int j = G * 128 + ub + lr;
      bias[G] = bih[l * G4H_ + j] + bhh[l * G4H_ + j];
#pragma unroll
      for (int kt = 0; kt < 4; ++kt) {
        wi[G][kt] = *(const f16x8*)(wip + (size_t)j * H_ + kt * 32 + k0);
        wh[G][kt] = *(const f16x8*)(whp + (size_t)j * H_ + kt * 32 + k0);
      }
    }
  }

  // ---- c state (fp32), private coalesced layout ----
  float cst[4];
  float* csp = CS + ((((size_t)l * NCH + chunk) * 8 + wave) * 64 + lane) * 4;
  if (ct == 0) {
#pragma unroll
    for (int r = 0; r < 4; ++r) cst[r] = 0.0f;
  } else {
#pragma unroll
    for (int r = 0; r < 4; ++r) cst[r] = csp[r];
  }

  const size_t tile = (size_t)B_ * H_;  // one time step, halves
  const _Float16* Xin = (l == 0) ? (X0 + (size_t)ct * TS * tile)
                                 : (XR + ((size_t)(l - 1) * 2 + (ct & 1)) * TS * tile);
  _Float16* Xout = XR + ((size_t)l * 2 + (ct & 1)) * TS * tile;

  // ---- initial h fragments (last step of previous chunk, from own ring) ----
  f16x8 hf[4];
  if (ct == 0) {
#pragma unroll
    for (int kt = 0; kt < 4; ++kt)
#pragma unroll
      for (int i = 0; i < 8; ++i) hf[kt][i] = (_Float16)0.0f;
  } else {
    const _Float16* hp = XR + ((size_t)l * 2 + ((ct - 1) & 1)) * TS * tile +
                         (size_t)(TS - 1) * tile + (size_t)(chunk * 16 + lr) * H_ + k0;
#pragma unroll
    for (int kt = 0; kt < 4; ++kt) hf[kt] = *(const f16x8*)(hp + kt * 32);
  }

  __shared__ _Float16 hlds[16][136];  // [b][k], stride 272B: 2-way banks = free

  // prefetch x for tin = 0
  f16x8 xf[4];
  {
    const _Float16* xp = Xin + (size_t)(chunk * 16 + lr) * H_ + k0;
#pragma unroll
    for (int kt = 0; kt < 4; ++kt) xf[kt] = *(const f16x8*)(xp + kt * 32);
  }

  for (int tin = 0; tin < TS; ++tin) {
    // prefetch next step's x (hidden under MFMAs)
    f16x8 xn[4];
    if (tin + 1 < TS) {
      const _Float16* xp = Xin + (size_t)(tin + 1) * tile + (size_t)(chunk * 16 + lr) * H_ + k0;
#pragma unroll
      for (int kt = 0; kt < 4; ++kt) xn[kt] = *(const f16x8*)(xp + kt * 32);
    }

    f32x4 acc[4];
#pragma unroll
    for (int G = 0; G < 4; ++G) {
      float bv = bias[G];
      acc[G][0] = bv; acc[G][1] = bv; acc[G][2] = bv; acc[G][3] = bv;
    }
#pragma unroll
    for (int kt = 0; kt < 4; ++kt)
#pragma unroll
      for (int G = 0; G < 4; ++G)
        acc[G] = __builtin_amdgcn_mfma_f32_16x16x32_f16(xf[kt], wi[G][kt], acc[G], 0, 0, 0);
#pragma unroll
    for (int kt = 0; kt < 4; ++kt)
#pragma unroll
      for (int G = 0; G < 4; ++G)
        acc[G] = __builtin_amdgcn_mfma_f32_16x16x32_f16(hf[kt], wh[G][kt], acc[G], 0, 0, 0);

    // gates: lane has (b = lhi*4+r, u = ub+lr) for all 4 gates at same position
    float hnew[4];
#pragma unroll
    for (int r = 0; r < 4; ++r) {
      float iv = fast_sig(acc[0][r]);
      float fv = fast_sig(acc[1][r]);
      float gv = fast_tanh(acc[2][r]);
      float ov = fast_sig(acc[3][r]);
      float c = fv * cst[r] + iv * gv;
      cst[r] = c;
      hnew[r] = ov * fast_tanh(c);
    }

    __syncthreads();  // previous step's hlds reads done
#pragma unroll
    for (int r = 0; r < 4; ++r) hlds[lhi * 4 + r][ub + lr] = (_Float16)hnew[r];
    __syncthreads();  // hlds fully written

    // h fragments for next step
#pragma unroll
    for (int kt = 0; kt < 4; ++kt) hf[kt] = *(const f16x8*)&hlds[lr][kt * 32 + k0];

    // cooperative coalesced publish of h tile to next layer's ring
    {
      int tid = threadIdx.x;
      int row = tid >> 5, seg = tid & 31;
      *(f16x4*)(Xout + (size_t)tin * tile + (size_t)(chunk * 16 + row) * H_ + seg * 4) =
          *(const f16x4*)&hlds[row][seg * 4];
    }
    // final layer: fp32 output (pre-rounding values)
    if (l == L_ - 1) {
      size_t t = (size_t)ct * TS + tin;
#pragma unroll
      for (int r = 0; r < 4; ++r)
        out_h[(t * B_ + (size_t)(chunk * 16 + lhi * 4 + r)) * H_ + ub + lr] = hnew[r];
    }
    if (tin + 1 < TS) {
#pragma unroll
      for (int kt = 0; kt < 4; ++kt) xf[kt] = xn[kt];
    }
  }

#pragma unroll
  for (int r = 0; r < 4; ++r) csp[r] = cst[r];
}

extern "C" void kernel_launch(void* const* d_in, const int* in_sizes, int n_in,
                              void* d_out, int out_size, void* d_ws, size_t ws_size,
                              hipStream_t stream) {
  const int* xids = (const int*)d_in[0];
  const float* emb = (const float*)d_in[1];
  const float* Wih = (const float*)d_in[2];
  const float* Whh = (const float*)d_in[3];
  const float* bih = (const float*)d_in[4];
  const float* bhh = (const float*)d_in[5];
  float* out = (float*)d_out;
  float* out_h = out;                              // output 0: [T,B,H]
  float* out_emb = out + (size_t)T_ * B_ * H_;     // output 1: [T,B,H]

  char* ws = (char*)d_ws;
  const size_t X0_BYTES = (size_t)T_ * B_ * H_ * 2;           // 33.6 MB
  const size_t XR_BYTES = (size_t)L_ * 2 * TS * B_ * H_ * 2;  // 41.9 MB
  const size_t CS_BYTES = (size_t)L_ * NCH * 8 * 64 * 4 * 4;  // 5.2 MB
  const size_t WF_BYTES = (size_t)L_ * G4H_ * H_ * 2;         // 2.6 MB
  _Float16* X0 = (_Float16*)ws;
  _Float16* XR = (_Float16*)(ws + X0_BYTES);
  float* CS = (float*)(ws + X0_BYTES + XR_BYTES);
  _Float16* Wif = (_Float16*)(ws + X0_BYTES + XR_BYTES + CS_BYTES);
  _Float16* Whf = (_Float16*)(ws + X0_BYTES + XR_BYTES + CS_BYTES + WF_BYTES);

  wconv_kernel<<<(L_ * G4H_ * H_ + 255) / 256, 256, 0, stream>>>(Wih, Whh, Wif, Whf);
  emb_kernel<<<T_ * B_, H_, 0, stream>>>(xids, emb, out_emb, X0);

  for (int s = 0; s < NSLOT; ++s) {
    int l0 = (s - (NCT - 1) > 0) ? (s - (NCT - 1)) : 0;
    int l1 = (s < L_ - 1) ? s : (L_ - 1);
    int nt = l1 - l0 + 1;
    lstm_slot_kernel<<<nt * NCH, 512, 0, stream>>>(Wif, Whf, bih, bhh, X0, XR, CS, out_h, s, l0);
  }
}

// Round 3
// 2684.478 us; speedup vs baseline: 1.0753x; 1.0753x over previous
//
#include <hip/hip_runtime.h>

#define T_ 1024
#define B_ 128
#define H_ 128
#define L_ 20
#define G4H_ 512
#define NCH 8              // batch chunks of 16 rows
#define RING 64            // ring depth (steps) per (layer,chunk) channel
#define GRP 4              // publish granularity (steps)
#define FSTRIDE 32         // flag padding: 32 ints = 128 B per flag

typedef _Float16 f16x8 __attribute__((ext_vector_type(8)));
typedef _Float16 f16x4 __attribute__((ext_vector_type(4)));
typedef float f32x4 __attribute__((ext_vector_type(4)));

__device__ __forceinline__ float fast_sig(float x) {
  float e = __builtin_amdgcn_exp2f(-1.44269504f * x);
  return __builtin_amdgcn_rcpf(1.0f + e);
}
__device__ __forceinline__ float fast_tanh(float x) {
  float e = __builtin_amdgcn_exp2f(2.88539008f * x);  // e^{2x}
  return 1.0f - 2.0f * __builtin_amdgcn_rcpf(e + 1.0f);
}

// fp32 -> fp16 weight copies in workspace (re-done every launch; deterministic)
__global__ void wconv_kernel(const float* __restrict__ Wih, const float* __restrict__ Whh,
                             _Float16* __restrict__ Wif, _Float16* __restrict__ Whf) {
  int i = blockIdx.x * 256 + threadIdx.x;
  if (i < L_ * G4H_ * H_) {
    Wif[i] = (_Float16)Wih[i];
    Whf[i] = (_Float16)Whh[i];
  }
}

// embedding gather: fp32 copy to d_out (output 1) + fp16 copy as layer-0 input
__global__ void emb_kernel(const int* __restrict__ xids, const float* __restrict__ emb,
                           float* __restrict__ out_emb, _Float16* __restrict__ X0) {
  int row = blockIdx.x;       // t*B + b
  int d = threadIdx.x;        // 0..127
  int tok = xids[row];
  float v = emb[(size_t)tok * H_ + d];
  out_emb[(size_t)row * H_ + d] = v;
  X0[(size_t)row * H_ + d] = (_Float16)v;
}

// Persistent wavefront-pipelined LSTM. One block per (layer, batch-chunk).
// Weights + c/h state live in registers for all 1024 steps. h handed to layer
// l+1 via RING-deep fp16 ring + progress flags every GRP steps.
// Flag protocol (deadlock-audited):
//   - EVERY layer publishes rdy[l] = tg+GRP after finishing group tg
//     (last layer included — R2 deadlocked because it didn't).
//   - data wait (l>0): ACQUIRE on rdy[l-1] >= tg+GRP (orders ring reads).
//   - backpressure (l<L-1): RELAXED poll rdy[l+1] >= tg+2*GRP-RING.
__launch_bounds__(512, 2)
__global__ void lstm_persist_kernel(const _Float16* __restrict__ Wif,
                                    const _Float16* __restrict__ Whf,
                                    const float* __restrict__ bih,
                                    const float* __restrict__ bhh,
                                    const _Float16* __restrict__ X0,
                                    _Float16* __restrict__ XR,
                                    float* __restrict__ out_h,
                                    int* __restrict__ rdy) {
  const int l = blockIdx.x >> 3;
  const int chunk = blockIdx.x & 7;
  const int lane = threadIdx.x & 63;
  const int wave = threadIdx.x >> 6;
  const int lr = lane & 15;    // A-frag row / B-frag col / D col
  const int lhi = lane >> 4;   // k-group; D row group
  const int k0 = lhi * 8;
  const int ub = wave * 16;    // hidden slice base

  // ---- weight fragments in registers: lane holds W[j=G*128+ub+lr][kt*32+k0..+8]
  f16x8 wi[4][4], wh[4][4];
  float bias[4];
  {
    const _Float16* wip = Wif + (size_t)l * G4H_ * H_;
    const _Float16* whp = Whf + (size_t)l * G4H_ * H_;
#pragma unroll
    for (int G = 0; G < 4; ++G) {
      int j = G * 128 + ub + lr;
      bias[G] = bih[l * G4H_ + j] + bhh[l * G4H_ + j];
#pragma unroll
      for (int kt = 0; kt < 4; ++kt) {
        wi[G][kt] = *(const f16x8*)(wip + (size_t)j * H_ + kt * 32 + k0);
        wh[G][kt] = *(const f16x8*)(whp + (size_t)j * H_ + kt * 32 + k0);
      }
    }
  }

  float cst[4] = {0.f, 0.f, 0.f, 0.f};
  f16x8 hf[4];
#pragma unroll
  for (int kt = 0; kt < 4; ++kt)
#pragma unroll
    for (int i = 0; i < 8; ++i) hf[kt][i] = (_Float16)0.0f;

  __shared__ _Float16 hlds[2][16][136];  // double-buffered h tile [b][k]

  const size_t tile16 = (size_t)16 * H_;  // 2048 elems = 4KB per step-slice
  const _Float16* ring_in =
      (l > 0) ? XR + (size_t)((l - 1) * NCH + chunk) * RING * tile16 : X0;
  _Float16* ring_out = XR + (size_t)(l * NCH + chunk) * RING * tile16;

  int* rin = rdy + ((l - 1) * NCH + chunk) * FSTRIDE;    // valid only if l>0
  int* rout = rdy + (l * NCH + chunk) * FSTRIDE;
  int* rcons = rdy + ((l + 1) * NCH + chunk) * FSTRIDE;  // valid only if l<L-1

  f16x8 xf[4];
  if (l == 0) {  // step-0 input always available
    const _Float16* xp = X0 + ((size_t)0 * B_ + chunk * 16 + lr) * H_ + k0;
#pragma unroll
    for (int kt = 0; kt < 4; ++kt) xf[kt] = *(const f16x8*)(xp + kt * 32);
  }

  for (int tg = 0; tg < T_; tg += GRP) {
    // ---- flag waits (wave 0 only), then block barrier ----
    if (wave == 0) {
      if (l > 0) {  // data-ready: acquire (orders our ring reads after theirs)
        while (__hip_atomic_load(rin, __ATOMIC_ACQUIRE, __HIP_MEMORY_SCOPE_AGENT) < tg + GRP)
          __builtin_amdgcn_s_sleep(2);
      }
      if (l < L_ - 1) {  // backpressure: relaxed (no data flows this way)
        int need = tg + 2 * GRP - RING;  // one-group safety margin
        if (need > 0) {
          while (__hip_atomic_load(rcons, __ATOMIC_RELAXED, __HIP_MEMORY_SCOPE_AGENT) < need)
            __builtin_amdgcn_s_sleep(2);
        }
      }
    }
    __syncthreads();

    if (l > 0) {  // first step of group: load x now that flag passed
      const _Float16* xp = ring_in + (size_t)(tg & (RING - 1)) * tile16 + (size_t)lr * H_ + k0;
#pragma unroll
      for (int kt = 0; kt < 4; ++kt) xf[kt] = *(const f16x8*)(xp + kt * 32);
    }

    for (int ti = 0; ti < GRP; ++ti) {
      const int t = tg + ti;

      // prefetch next step's x (within group; l==0 may cross groups)
      f16x8 xn[4];
      const bool pre = (l == 0) ? (t + 1 < T_) : (ti + 1 < GRP);
      if (pre) {
        const _Float16* xp =
            (l == 0) ? X0 + ((size_t)(t + 1) * B_ + chunk * 16 + lr) * H_ + k0
                     : ring_in + (size_t)((t + 1) & (RING - 1)) * tile16 + (size_t)lr * H_ + k0;
#pragma unroll
        for (int kt = 0; kt < 4; ++kt) xn[kt] = *(const f16x8*)(xp + kt * 32);
      }

      f32x4 acc[4];
#pragma unroll
      for (int G = 0; G < 4; ++G) {
        float bv = bias[G];
        acc[G][0] = bv; acc[G][1] = bv; acc[G][2] = bv; acc[G][3] = bv;
      }
#pragma unroll
      for (int kt = 0; kt < 4; ++kt)
#pragma unroll
        for (int G = 0; G < 4; ++G)
          acc[G] = __builtin_amdgcn_mfma_f32_16x16x32_f16(xf[kt], wi[G][kt], acc[G], 0, 0, 0);
#pragma unroll
      for (int kt = 0; kt < 4; ++kt)
#pragma unroll
        for (int G = 0; G < 4; ++G)
          acc[G] = __builtin_amdgcn_mfma_f32_16x16x32_f16(hf[kt], wh[G][kt], acc[G], 0, 0, 0);

      // gates: lane has (b = chunk*16 + lhi*4+r, u = ub+lr), all 4 gates local
      float hnew[4];
#pragma unroll
      for (int r = 0; r < 4; ++r) {
        float iv = fast_sig(acc[0][r]);
        float fv = fast_sig(acc[1][r]);
        float gv = fast_tanh(acc[2][r]);
        float ov = fast_sig(acc[3][r]);
        float c = fv * cst[r] + iv * gv;
        cst[r] = c;
        hnew[r] = ov * fast_tanh(c);
      }

      const int pb = t & 1;
#pragma unroll
      for (int r = 0; r < 4; ++r) hlds[pb][lhi * 4 + r][ub + lr] = (_Float16)hnew[r];
      __syncthreads();
#pragma unroll
      for (int kt = 0; kt < 4; ++kt) hf[kt] = *(const f16x8*)&hlds[pb][lr][kt * 32 + k0];

      if (l < L_ - 1) {
        // cooperative coalesced publish: 512 threads x 8B = full 4KB slice
        const int tid = threadIdx.x;
        const int row = tid >> 5, seg = tid & 31;
        *(f16x4*)(ring_out + (size_t)(t & (RING - 1)) * tile16 + (size_t)row * H_ + seg * 4) =
            *(const f16x4*)&hlds[pb][row][seg * 4];
      } else {
        // final layer: fp32 output (pre-rounding values)
#pragma unroll
        for (int r = 0; r < 4; ++r)
          out_h[((size_t)t * B_ + chunk * 16 + lhi * 4 + r) * H_ + ub + lr] = hnew[r];
      }

      if (pre) {
#pragma unroll
        for (int kt = 0; kt < 4; ++kt) xf[kt] = xn[kt];
      }
    }

    // ---- publish progress: EVERY layer, every group ----
    __syncthreads();  // all waves' ring stores issued & ordered before flag
    if (threadIdx.x == 0) {
      if (l < L_ - 1)
        __hip_atomic_store(rout, tg + GRP, __ATOMIC_RELEASE, __HIP_MEMORY_SCOPE_AGENT);
      else  // backpressure-only flag: no data to order
        __hip_atomic_store(rout, tg + GRP, __ATOMIC_RELAXED, __HIP_MEMORY_SCOPE_AGENT);
    }
  }
}

extern "C" void kernel_launch(void* const* d_in, const int* in_sizes, int n_in,
                              void* d_out, int out_size, void* d_ws, size_t ws_size,
                              hipStream_t stream) {
  const int* xids = (const int*)d_in[0];
  const float* emb = (const float*)d_in[1];
  const float* Wih = (const float*)d_in[2];
  const float* Whh = (const float*)d_in[3];
  const float* bih = (const float*)d_in[4];
  const float* bhh = (const float*)d_in[5];
  float* out = (float*)d_out;
  float* out_h = out;                              // output 0: [T,B,H]
  float* out_emb = out + (size_t)T_ * B_ * H_;     // output 1: [T,B,H]

  char* ws = (char*)d_ws;
  const size_t RDY_BYTES = (size_t)L_ * NCH * FSTRIDE * 4;        // 25.6 KB
  const size_t X0_BYTES = (size_t)T_ * B_ * H_ * 2;               // 33.6 MB
  const size_t XR_BYTES = (size_t)L_ * NCH * RING * 16 * H_ * 2;  // 40 MB
  const size_t WF_BYTES = (size_t)L_ * G4H_ * H_ * 2;             // 2.6 MB
  int* rdyp = (int*)ws;
  _Float16* X0 = (_Float16*)(ws + RDY_BYTES);
  _Float16* XR = (_Float16*)(ws + RDY_BYTES + X0_BYTES);
  _Float16* Wif = (_Float16*)(ws + RDY_BYTES + X0_BYTES + XR_BYTES);
  _Float16* Whf = (_Float16*)(ws + RDY_BYTES + X0_BYTES + XR_BYTES + WF_BYTES);

  hipMemsetAsync(rdyp, 0, RDY_BYTES, stream);
  wconv_kernel<<<(L_ * G4H_ * H_ + 255) / 256, 256, 0, stream>>>(Wih, Whh, Wif, Whf);
  emb_kernel<<<T_ * B_, H_, 0, stream>>>(xids, emb, out_emb, X0);

  void* args[] = {(void*)&Wif, (void*)&Whf, (void*)&bih, (void*)&bhh,
                  (void*)&X0,  (void*)&XR,  (void*)&out_h, (void*)&rdyp};
  hipLaunchCooperativeKernel((void*)lstm_persist_kernel, dim3(L_ * NCH), dim3(512),
                             args, 0, stream);
}